// Round 1
// baseline (920.380 us; speedup 1.0000x reference)
//
#include <hip/hip_runtime.h>
#include <cstddef>

#define D_MODEL 1024
#define D_STATE 16
#define DT_RANK 64
#define BATCH 4
#define SEQ 4096
#define NPROJ 96                 // DT_RANK + 2*D_STATE
#define M_TOTAL (BATCH * SEQ)    // 16384
#define NCHUNK 64
#define CLEN 64                  // SEQ / NCHUNK

__device__ __forceinline__ float softplus_f(float v) {
    // stable log1p(exp(v)) — matches jax.nn.softplus
    return (v > 0.0f) ? v + log1pf(expf(-v)) : log1pf(expf(v));
}

// ---------------- GEMM1: xp[m, p] = sum_k x[m,k] * Wx[p,k] ----------------
// M=16384, N=96, K=1024.  BM=64, BN=96 (full), BK=32. 256 thr, 4x6 per thread.
__global__ __launch_bounds__(256) void proj_kernel(const float* __restrict__ x,
                                                   const float* __restrict__ W,
                                                   float* __restrict__ xp) {
    __shared__ float xs[64][33];
    __shared__ float ws[96][33];
    const int tid  = threadIdx.x;
    const int row0 = blockIdx.x * 64;
    const int ty = tid >> 4;   // rows ty*4 .. +3
    const int tx = tid & 15;   // cols tx*6 .. +5

    float acc[4][6];
#pragma unroll
    for (int i = 0; i < 4; ++i)
#pragma unroll
        for (int j = 0; j < 6; ++j) acc[i][j] = 0.0f;

    for (int k0 = 0; k0 < 1024; k0 += 32) {
        // stage x tile: 64 rows x 32 k  (512 float4, 2 per thread)
        for (int i = tid; i < 64 * 8; i += 256) {
            int r = i >> 3, c4 = i & 7;
            float4 v = *reinterpret_cast<const float4*>(
                &x[(size_t)(row0 + r) * 1024 + k0 + c4 * 4]);
            xs[r][c4 * 4 + 0] = v.x; xs[r][c4 * 4 + 1] = v.y;
            xs[r][c4 * 4 + 2] = v.z; xs[r][c4 * 4 + 3] = v.w;
        }
        // stage W tile: 96 rows x 32 k  (768 float4, 3 per thread)
        for (int i = tid; i < 96 * 8; i += 256) {
            int r = i >> 3, c4 = i & 7;
            float4 v = *reinterpret_cast<const float4*>(
                &W[(size_t)r * 1024 + k0 + c4 * 4]);
            ws[r][c4 * 4 + 0] = v.x; ws[r][c4 * 4 + 1] = v.y;
            ws[r][c4 * 4 + 2] = v.z; ws[r][c4 * 4 + 3] = v.w;
        }
        __syncthreads();
#pragma unroll
        for (int k = 0; k < 32; ++k) {
            float a[4], b[6];
#pragma unroll
            for (int i = 0; i < 4; ++i) a[i] = xs[ty * 4 + i][k];
#pragma unroll
            for (int j = 0; j < 6; ++j) b[j] = ws[tx * 6 + j][k];
#pragma unroll
            for (int i = 0; i < 4; ++i)
#pragma unroll
                for (int j = 0; j < 6; ++j) acc[i][j] = fmaf(a[i], b[j], acc[i][j]);
        }
        __syncthreads();
    }
#pragma unroll
    for (int i = 0; i < 4; ++i) {
        size_t rbase = (size_t)(row0 + ty * 4 + i) * NPROJ;
#pragma unroll
        for (int j = 0; j < 6; ++j) xp[rbase + tx * 6 + j] = acc[i][j];
    }
}

// ------- GEMM2: delta[m,d] = softplus( sum_r xp[m,r]*Wd[d,r] + b_dt[d] ) ----
// M=16384, N=1024, K=64 (single pass). BM=64, BN=64. 256 thr, 4x4 per thread.
__global__ __launch_bounds__(256) void delta_kernel(const float* __restrict__ xp,
                                                    const float* __restrict__ Wd,
                                                    const float* __restrict__ b_dt,
                                                    float* __restrict__ delta) {
    __shared__ float as[64][65];
    __shared__ float bs[64][65];
    const int tid  = threadIdx.x;
    const int row0 = blockIdx.x * 64;
    const int col0 = blockIdx.y * 64;
    const int ty = tid >> 4;   // rows ty*4..+3
    const int tx = tid & 15;   // cols tx*4..+3

    // stage A tile: 64 rows x 64 k from xp (first 64 of each 96-row) : 1024 float4
    for (int i = tid; i < 64 * 16; i += 256) {
        int r = i >> 4, c4 = i & 15;
        float4 v = *reinterpret_cast<const float4*>(
            &xp[(size_t)(row0 + r) * NPROJ + c4 * 4]);
        as[r][c4 * 4 + 0] = v.x; as[r][c4 * 4 + 1] = v.y;
        as[r][c4 * 4 + 2] = v.z; as[r][c4 * 4 + 3] = v.w;
    }
    // stage W tile: 64 rows (cols of output) x 64 k : rows contiguous
    for (int i = tid; i < 64 * 16; i += 256) {
        int r = i >> 4, c4 = i & 15;
        float4 v = *reinterpret_cast<const float4*>(
            &Wd[(size_t)(col0 + r) * 64 + c4 * 4]);
        bs[r][c4 * 4 + 0] = v.x; bs[r][c4 * 4 + 1] = v.y;
        bs[r][c4 * 4 + 2] = v.z; bs[r][c4 * 4 + 3] = v.w;
    }
    __syncthreads();

    float acc[4][4];
#pragma unroll
    for (int i = 0; i < 4; ++i)
#pragma unroll
        for (int j = 0; j < 4; ++j) acc[i][j] = 0.0f;

#pragma unroll
    for (int k = 0; k < 64; ++k) {
        float a[4], b[4];
#pragma unroll
        for (int i = 0; i < 4; ++i) a[i] = as[ty * 4 + i][k];
#pragma unroll
        for (int j = 0; j < 4; ++j) b[j] = bs[tx * 4 + j][k];
#pragma unroll
        for (int i = 0; i < 4; ++i)
#pragma unroll
            for (int j = 0; j < 4; ++j) acc[i][j] = fmaf(a[i], b[j], acc[i][j]);
    }

#pragma unroll
    for (int i = 0; i < 4; ++i) {
        int row = row0 + ty * 4 + i;
        int col = col0 + tx * 4;
        float4 o;
        o.x = softplus_f(acc[i][0] + b_dt[col + 0]);
        o.y = softplus_f(acc[i][1] + b_dt[col + 1]);
        o.z = softplus_f(acc[i][2] + b_dt[col + 2]);
        o.w = softplus_f(acc[i][3] + b_dt[col + 3]);
        *reinterpret_cast<float4*>(&delta[(size_t)row * D_MODEL + col]) = o;
    }
}

// ---------------- Scan pass A: per-chunk transfer (Prod a, h_local) --------
// block: 256 thr = 16 d_local x 16 n ; grid (NCHUNK, D_MODEL/16, BATCH)
__global__ __launch_bounds__(256) void scanA_kernel(const float* __restrict__ x,
                                                    const float* __restrict__ xp,
                                                    const float* __restrict__ delta,
                                                    const float* __restrict__ A_log,
                                                    float* __restrict__ P,
                                                    float* __restrict__ H) {
    const int chunk = blockIdx.x;
    const int dg    = blockIdx.y;
    const int b     = blockIdx.z;
    const int tid   = threadIdx.x;
    const int n  = tid & 15;
    const int dl = tid >> 4;
    const int d  = dg * 16 + dl;

    const float Av = -expf(A_log[(size_t)d * D_STATE + n]);
    float h = 0.0f, Pv = 1.0f;

    const int sbase = chunk * CLEN;
    size_t xbase = ((size_t)b * SEQ + sbase) * D_MODEL + d;
    size_t pbase = ((size_t)b * SEQ + sbase) * NPROJ;

    for (int j = 0; j < CLEN; ++j) {
        float dv = delta[xbase + (size_t)j * D_MODEL];
        float xv = x[xbase + (size_t)j * D_MODEL];
        float Bv = xp[pbase + (size_t)j * NPROJ + DT_RANK + n];
        float a  = expf(dv * Av);
        h  = fmaf(a, h, dv * xv * Bv);
        Pv *= a;
    }
    size_t idx = (((size_t)chunk * BATCH + b) * D_MODEL + d) * D_STATE + n;
    P[idx] = Pv;
    H[idx] = h;
}

// ---------------- Scan pass B: inter-chunk scan; rewrites P <- carry-in ----
__global__ __launch_bounds__(256) void scanB_kernel(float* __restrict__ P,
                                                    const float* __restrict__ H) {
    const int t = blockIdx.x * 256 + threadIdx.x;   // (b*1024+d)*16+n
    float carry = 0.0f;
    for (int c = 0; c < NCHUNK; ++c) {
        size_t idx = (size_t)c * (BATCH * D_MODEL * D_STATE) + t;
        float p  = P[idx];
        float hh = H[idx];
        P[idx] = carry;                       // carry-in for this chunk
        carry = fmaf(p, carry, hh);
    }
}

// ---------------- Scan pass C: replay with carry-in, produce y -------------
__global__ __launch_bounds__(256) void scanC_kernel(const float* __restrict__ x,
                                                    const float* __restrict__ xp,
                                                    const float* __restrict__ delta,
                                                    const float* __restrict__ A_log,
                                                    const float* __restrict__ Dvec,
                                                    const float* __restrict__ Hin,
                                                    float* __restrict__ out) {
    const int chunk = blockIdx.x;
    const int dg    = blockIdx.y;
    const int b     = blockIdx.z;
    const int tid   = threadIdx.x;
    const int n  = tid & 15;
    const int dl = tid >> 4;
    const int d  = dg * 16 + dl;

    const float Av = -expf(A_log[(size_t)d * D_STATE + n]);
    const float Dv = Dvec[d];

    size_t hidx = (((size_t)chunk * BATCH + b) * D_MODEL + d) * D_STATE + n;
    float h = Hin[hidx];

    const int sbase = chunk * CLEN;
    size_t xbase = ((size_t)b * SEQ + sbase) * D_MODEL + d;
    size_t pbase = ((size_t)b * SEQ + sbase) * NPROJ;

    for (int j = 0; j < CLEN; ++j) {
        float dv = delta[xbase + (size_t)j * D_MODEL];
        float xv = x[xbase + (size_t)j * D_MODEL];
        float Bv = xp[pbase + (size_t)j * NPROJ + DT_RANK + n];
        float Cv = xp[pbase + (size_t)j * NPROJ + DT_RANK + D_STATE + n];
        float a  = expf(dv * Av);
        h = fmaf(a, h, dv * xv * Bv);
        float p = h * Cv;
        // reduce over n (16-lane groups within the wave)
        p += __shfl_xor(p, 1);
        p += __shfl_xor(p, 2);
        p += __shfl_xor(p, 4);
        p += __shfl_xor(p, 8);
        if (n == 0) out[xbase + (size_t)j * D_MODEL] = fmaf(xv, Dv, p);
    }
}

extern "C" void kernel_launch(void* const* d_in, const int* in_sizes, int n_in,
                              void* d_out, int out_size, void* d_ws, size_t ws_size,
                              hipStream_t stream) {
    const float* x    = (const float*)d_in[0];
    const float* Wx   = (const float*)d_in[1];
    const float* Wd   = (const float*)d_in[2];
    const float* bdt  = (const float*)d_in[3];
    const float* Alog = (const float*)d_in[4];
    const float* Dv   = (const float*)d_in[5];
    float* out = (float*)d_out;

    float* ws    = (float*)d_ws;
    float* xp    = ws;                                        // 16384*96
    float* delta = xp + (size_t)M_TOTAL * NPROJ;              // 16384*1024
    float* P     = delta + (size_t)M_TOTAL * D_MODEL;         // 64*4*1024*16
    float* H     = P + (size_t)NCHUNK * BATCH * D_MODEL * D_STATE;

    proj_kernel<<<dim3(M_TOTAL / 64), 256, 0, stream>>>(x, Wx, xp);
    delta_kernel<<<dim3(M_TOTAL / 64, D_MODEL / 64), 256, 0, stream>>>(xp, Wd, bdt, delta);
    scanA_kernel<<<dim3(NCHUNK, D_MODEL / 16, BATCH), 256, 0, stream>>>(x, xp, delta, Alog, P, H);
    scanB_kernel<<<dim3((BATCH * D_MODEL * D_STATE) / 256), 256, 0, stream>>>(P, H);
    scanC_kernel<<<dim3(NCHUNK, D_MODEL / 16, BATCH), 256, 0, stream>>>(x, xp, delta, Alog, Dv, P, out);
}

// Round 3
// 495.391 us; speedup vs baseline: 1.8579x; 1.8579x over previous
//
#include <hip/hip_runtime.h>
#include <cstddef>

#define D_MODEL 1024
#define D_STATE 16
#define DT_RANK 64
#define BATCH 4
#define SEQ 4096
#define NPROJ 96                 // DT_RANK + 2*D_STATE
#define M_TOTAL (BATCH * SEQ)    // 16384
#define NCHUNK 64
#define CLEN 64                  // SEQ / NCHUNK

__device__ __forceinline__ float softplus_fast(float v) {
    // max(v,0) + log(1+exp(-|v|)) — stable, hardware exp/log (err ~1e-6, thr=4.0)
    return fmaxf(v, 0.0f) + __logf(1.0f + __expf(-fabsf(v)));
}

// ---------------- GEMM1: xp[m,p] = sum_k x[m,k] * Wx[p,k] ----------------
// M=16384, N=96, K=1024. BM=64, BN=96, BK=32. 128 thr, 8x6 per thread.
// x staged TRANSPOSED [k][row] so A-fragments load as ds_read_b128.
__global__ __launch_bounds__(128) void proj_kernel(const float* __restrict__ x,
                                                   const float* __restrict__ W,
                                                   float* __restrict__ xp) {
    __shared__ float xs_t[32][68];   // [k][row], stride 68 -> 16B-aligned rows, spread banks
    __shared__ float ws[96][33];     // [row][k]
    const int tid  = threadIdx.x;
    const int row0 = blockIdx.x * 64;
    const int ty = tid >> 4;   // 0..7 -> rows ty*8..+7
    const int tx = tid & 15;   // cols tx*6..+5

    float acc[8][6];
#pragma unroll
    for (int i = 0; i < 8; ++i)
#pragma unroll
        for (int j = 0; j < 6; ++j) acc[i][j] = 0.0f;

    for (int k0 = 0; k0 < 1024; k0 += 32) {
        // stage x tile transposed: 64 rows x 32 k (512 float4, 4/thread)
        for (int i = tid; i < 64 * 8; i += 128) {
            int r = i >> 3, c4 = i & 7;
            float4 v = *reinterpret_cast<const float4*>(
                &x[(size_t)(row0 + r) * 1024 + k0 + c4 * 4]);
            xs_t[c4 * 4 + 0][r] = v.x; xs_t[c4 * 4 + 1][r] = v.y;
            xs_t[c4 * 4 + 2][r] = v.z; xs_t[c4 * 4 + 3][r] = v.w;
        }
        // stage W tile row-major: 96 rows x 32 k (768 float4, 6/thread)
        for (int i = tid; i < 96 * 8; i += 128) {
            int r = i >> 3, c4 = i & 7;
            float4 v = *reinterpret_cast<const float4*>(
                &W[(size_t)r * 1024 + k0 + c4 * 4]);
            ws[r][c4 * 4 + 0] = v.x; ws[r][c4 * 4 + 1] = v.y;
            ws[r][c4 * 4 + 2] = v.z; ws[r][c4 * 4 + 3] = v.w;
        }
        __syncthreads();
#pragma unroll 4
        for (int k = 0; k < 32; ++k) {
            float4 a0 = *reinterpret_cast<const float4*>(&xs_t[k][ty * 8]);
            float4 a1 = *reinterpret_cast<const float4*>(&xs_t[k][ty * 8 + 4]);
            float a[8] = {a0.x, a0.y, a0.z, a0.w, a1.x, a1.y, a1.z, a1.w};
            float b[6];
#pragma unroll
            for (int j = 0; j < 6; ++j) b[j] = ws[tx * 6 + j][k];
#pragma unroll
            for (int i = 0; i < 8; ++i)
#pragma unroll
                for (int j = 0; j < 6; ++j) acc[i][j] = fmaf(a[i], b[j], acc[i][j]);
        }
        __syncthreads();
    }
#pragma unroll
    for (int i = 0; i < 8; ++i) {
        size_t rbase = (size_t)(row0 + ty * 8 + i) * NPROJ;
#pragma unroll
        for (int j = 0; j < 6; ++j) xp[rbase + tx * 6 + j] = acc[i][j];
    }
}

// ------- GEMM2: delta[m,d] = softplus( sum_r xp[m,r]*Wd[d,r] + b_dt[d] ) ----
// M=16384, N=1024, K=64. BM=128, BN=128, BK=32 (2 tiles). 256 thr, 8x8/thread.
// Both operands staged TRANSPOSED [k][mn] -> fragment loads are ds_read_b128.
__global__ __launch_bounds__(256) void delta_kernel(const float* __restrict__ xp,
                                                    const float* __restrict__ Wd,
                                                    const float* __restrict__ b_dt,
                                                    float* __restrict__ delta) {
    __shared__ float as_t[32][132];  // [k][row], stride 132 -> 16B aligned
    __shared__ float bs_t[32][132];  // [k][col]
    const int tid  = threadIdx.x;
    const int row0 = blockIdx.x * 128;
    const int col0 = blockIdx.y * 128;
    const int ty = tid >> 4;   // rows ty*8..+7
    const int tx = tid & 15;   // cols tx*8..+7

    float acc[8][8];
#pragma unroll
    for (int i = 0; i < 8; ++i)
#pragma unroll
        for (int j = 0; j < 8; ++j) acc[i][j] = 0.0f;

    for (int k0 = 0; k0 < 64; k0 += 32) {
        // stage A transposed: 128 rows x 32 k (1024 float4, 4/thread)
        for (int i = tid; i < 128 * 8; i += 256) {
            int r = i >> 3, c4 = i & 7;
            float4 v = *reinterpret_cast<const float4*>(
                &xp[(size_t)(row0 + r) * NPROJ + k0 + c4 * 4]);
            as_t[c4 * 4 + 0][r] = v.x; as_t[c4 * 4 + 1][r] = v.y;
            as_t[c4 * 4 + 2][r] = v.z; as_t[c4 * 4 + 3][r] = v.w;
        }
        // stage B transposed: 128 cols x 32 k
        for (int i = tid; i < 128 * 8; i += 256) {
            int r = i >> 3, c4 = i & 7;
            float4 v = *reinterpret_cast<const float4*>(
                &Wd[(size_t)(col0 + r) * 64 + k0 + c4 * 4]);
            bs_t[c4 * 4 + 0][r] = v.x; bs_t[c4 * 4 + 1][r] = v.y;
            bs_t[c4 * 4 + 2][r] = v.z; bs_t[c4 * 4 + 3][r] = v.w;
        }
        __syncthreads();
#pragma unroll 4
        for (int k = 0; k < 32; ++k) {
            float4 a0 = *reinterpret_cast<const float4*>(&as_t[k][ty * 8]);
            float4 a1 = *reinterpret_cast<const float4*>(&as_t[k][ty * 8 + 4]);
            float4 b0 = *reinterpret_cast<const float4*>(&bs_t[k][tx * 8]);
            float4 b1 = *reinterpret_cast<const float4*>(&bs_t[k][tx * 8 + 4]);
            float a[8] = {a0.x, a0.y, a0.z, a0.w, a1.x, a1.y, a1.z, a1.w};
            float b[8] = {b0.x, b0.y, b0.z, b0.w, b1.x, b1.y, b1.z, b1.w};
#pragma unroll
            for (int i = 0; i < 8; ++i)
#pragma unroll
                for (int j = 0; j < 8; ++j) acc[i][j] = fmaf(a[i], b[j], acc[i][j]);
        }
        __syncthreads();
    }

    float4 bias0 = *reinterpret_cast<const float4*>(&b_dt[col0 + tx * 8]);
    float4 bias1 = *reinterpret_cast<const float4*>(&b_dt[col0 + tx * 8 + 4]);
#pragma unroll
    for (int i = 0; i < 8; ++i) {
        int row = row0 + ty * 8 + i;
        float4 o0, o1;
        o0.x = softplus_fast(acc[i][0] + bias0.x);
        o0.y = softplus_fast(acc[i][1] + bias0.y);
        o0.z = softplus_fast(acc[i][2] + bias0.z);
        o0.w = softplus_fast(acc[i][3] + bias0.w);
        o1.x = softplus_fast(acc[i][4] + bias1.x);
        o1.y = softplus_fast(acc[i][5] + bias1.y);
        o1.z = softplus_fast(acc[i][6] + bias1.z);
        o1.w = softplus_fast(acc[i][7] + bias1.w);
        float* dst = &delta[(size_t)row * D_MODEL + col0 + tx * 8];
        *reinterpret_cast<float4*>(dst)     = o0;
        *reinterpret_cast<float4*>(dst + 4) = o1;
    }
}

// ---------------- Scan pass A: per-chunk transfer (Prod a, h_local) --------
// One thread owns all 16 n-states of one (b,d) chain within a chunk.
// grid (NCHUNK, D_MODEL/256, BATCH), 256 thr.
__global__ __launch_bounds__(256) void scanA_kernel(const float* __restrict__ x,
                                                    const float* __restrict__ xp,
                                                    const float* __restrict__ delta,
                                                    const float* __restrict__ A_log,
                                                    float* __restrict__ P,
                                                    float* __restrict__ H) {
    const int chunk = blockIdx.x;
    const int b     = blockIdx.z;
    const int d     = blockIdx.y * 256 + threadIdx.x;

    float Av[16];
    const float4* Arow = reinterpret_cast<const float4*>(A_log + (size_t)d * D_STATE);
#pragma unroll
    for (int q = 0; q < 4; ++q) {
        float4 v = Arow[q];
        Av[q * 4 + 0] = -__expf(v.x); Av[q * 4 + 1] = -__expf(v.y);
        Av[q * 4 + 2] = -__expf(v.z); Av[q * 4 + 3] = -__expf(v.w);
    }
    float h[16];
#pragma unroll
    for (int n = 0; n < 16; ++n) h[n] = 0.0f;
    float sdv = 0.0f;

    const size_t m0 = (size_t)b * SEQ + (size_t)chunk * CLEN;
#pragma unroll 2
    for (int j = 0; j < CLEN; ++j) {
        size_t m = m0 + j;
        float dv = delta[m * D_MODEL + d];
        float xv = x[m * D_MODEL + d];
        float dtx = dv * xv;
        const float4* Bp = reinterpret_cast<const float4*>(xp + m * NPROJ + DT_RANK);
        float Bv[16];
        {
            float4 v0 = Bp[0], v1 = Bp[1], v2 = Bp[2], v3 = Bp[3];
            Bv[0]=v0.x; Bv[1]=v0.y; Bv[2]=v0.z; Bv[3]=v0.w;
            Bv[4]=v1.x; Bv[5]=v1.y; Bv[6]=v1.z; Bv[7]=v1.w;
            Bv[8]=v2.x; Bv[9]=v2.y; Bv[10]=v2.z; Bv[11]=v2.w;
            Bv[12]=v3.x; Bv[13]=v3.y; Bv[14]=v3.z; Bv[15]=v3.w;
        }
        sdv += dv;
#pragma unroll
        for (int n = 0; n < 16; ++n) {
            float a = __expf(dv * Av[n]);
            h[n] = fmaf(a, h[n], dtx * Bv[n]);
        }
    }
    size_t idx = (((size_t)chunk * BATCH + b) * D_MODEL + d) * D_STATE;
    float4* Pp = reinterpret_cast<float4*>(P + idx);
    float4* Hp = reinterpret_cast<float4*>(H + idx);
#pragma unroll
    for (int q = 0; q < 4; ++q) {
        float4 pv, hv;
        pv.x = __expf(Av[q*4+0] * sdv); pv.y = __expf(Av[q*4+1] * sdv);
        pv.z = __expf(Av[q*4+2] * sdv); pv.w = __expf(Av[q*4+3] * sdv);
        hv.x = h[q*4+0]; hv.y = h[q*4+1]; hv.z = h[q*4+2]; hv.w = h[q*4+3];
        Pp[q] = pv; Hp[q] = hv;
    }
}

// ---------------- Scan pass B: inter-chunk scan; rewrites P <- carry-in ----
__global__ __launch_bounds__(256) void scanB_kernel(float* __restrict__ P,
                                                    const float* __restrict__ H) {
    const int t = blockIdx.x * 256 + threadIdx.x;   // (b*1024+d)*16+n
    float carry = 0.0f;
    for (int c = 0; c < NCHUNK; ++c) {
        size_t idx = (size_t)c * (BATCH * D_MODEL * D_STATE) + t;
        float p  = P[idx];
        float hh = H[idx];
        P[idx] = carry;                       // carry-in for this chunk
        carry = fmaf(p, carry, hh);
    }
}

// ---------------- Scan pass C: replay with carry-in, produce y -------------
__global__ __launch_bounds__(256) void scanC_kernel(const float* __restrict__ x,
                                                    const float* __restrict__ xp,
                                                    const float* __restrict__ delta,
                                                    const float* __restrict__ A_log,
                                                    const float* __restrict__ Dvec,
                                                    const float* __restrict__ Hin,
                                                    float* __restrict__ out) {
    const int chunk = blockIdx.x;
    const int b     = blockIdx.z;
    const int d     = blockIdx.y * 256 + threadIdx.x;

    float Av[16];
    const float4* Arow = reinterpret_cast<const float4*>(A_log + (size_t)d * D_STATE);
#pragma unroll
    for (int q = 0; q < 4; ++q) {
        float4 v = Arow[q];
        Av[q * 4 + 0] = -__expf(v.x); Av[q * 4 + 1] = -__expf(v.y);
        Av[q * 4 + 2] = -__expf(v.z); Av[q * 4 + 3] = -__expf(v.w);
    }
    const float Dv = Dvec[d];

    float h[16];
    size_t idx = (((size_t)chunk * BATCH + b) * D_MODEL + d) * D_STATE;
    const float4* Hp = reinterpret_cast<const float4*>(Hin + idx);
#pragma unroll
    for (int q = 0; q < 4; ++q) {
        float4 v = Hp[q];
        h[q*4+0] = v.x; h[q*4+1] = v.y; h[q*4+2] = v.z; h[q*4+3] = v.w;
    }

    const size_t m0 = (size_t)b * SEQ + (size_t)chunk * CLEN;
#pragma unroll 2
    for (int j = 0; j < CLEN; ++j) {
        size_t m = m0 + j;
        float dv = delta[m * D_MODEL + d];
        float xv = x[m * D_MODEL + d];
        float dtx = dv * xv;
        const float4* Bp = reinterpret_cast<const float4*>(xp + m * NPROJ + DT_RANK);
        float Bv[16], Cv[16];
        {
            float4 v0 = Bp[0], v1 = Bp[1], v2 = Bp[2], v3 = Bp[3];
            Bv[0]=v0.x; Bv[1]=v0.y; Bv[2]=v0.z; Bv[3]=v0.w;
            Bv[4]=v1.x; Bv[5]=v1.y; Bv[6]=v1.z; Bv[7]=v1.w;
            Bv[8]=v2.x; Bv[9]=v2.y; Bv[10]=v2.z; Bv[11]=v2.w;
            Bv[12]=v3.x; Bv[13]=v3.y; Bv[14]=v3.z; Bv[15]=v3.w;
            float4 c0 = Bp[4], c1 = Bp[5], c2 = Bp[6], c3 = Bp[7];
            Cv[0]=c0.x; Cv[1]=c0.y; Cv[2]=c0.z; Cv[3]=c0.w;
            Cv[4]=c1.x; Cv[5]=c1.y; Cv[6]=c1.z; Cv[7]=c1.w;
            Cv[8]=c2.x; Cv[9]=c2.y; Cv[10]=c2.z; Cv[11]=c2.w;
            Cv[12]=c3.x; Cv[13]=c3.y; Cv[14]=c3.z; Cv[15]=c3.w;
        }
        float y = 0.0f;
#pragma unroll
        for (int n = 0; n < 16; ++n) {
            float a = __expf(dv * Av[n]);
            h[n] = fmaf(a, h[n], dtx * Bv[n]);
            y = fmaf(h[n], Cv[n], y);
        }
        out[m * D_MODEL + d] = fmaf(xv, Dv, y);
    }
}

extern "C" void kernel_launch(void* const* d_in, const int* in_sizes, int n_in,
                              void* d_out, int out_size, void* d_ws, size_t ws_size,
                              hipStream_t stream) {
    const float* x    = (const float*)d_in[0];
    const float* Wx   = (const float*)d_in[1];
    const float* Wd   = (const float*)d_in[2];
    const float* bdt  = (const float*)d_in[3];
    const float* Alog = (const float*)d_in[4];
    const float* Dv   = (const float*)d_in[5];
    float* out = (float*)d_out;

    float* ws    = (float*)d_ws;
    float* xp    = ws;                                        // 16384*96
    float* delta = xp + (size_t)M_TOTAL * NPROJ;              // 16384*1024
    float* P     = delta + (size_t)M_TOTAL * D_MODEL;         // 64*4*1024*16
    float* H     = P + (size_t)NCHUNK * BATCH * D_MODEL * D_STATE;

    proj_kernel<<<dim3(M_TOTAL / 64), 128, 0, stream>>>(x, Wx, xp);
    delta_kernel<<<dim3(M_TOTAL / 128, D_MODEL / 128), 256, 0, stream>>>(xp, Wd, bdt, delta);
    scanA_kernel<<<dim3(NCHUNK, D_MODEL / 256, BATCH), 256, 0, stream>>>(x, xp, delta, Alog, P, H);
    scanB_kernel<<<dim3((BATCH * D_MODEL * D_STATE) / 256), 256, 0, stream>>>(P, H);
    scanC_kernel<<<dim3(NCHUNK, D_MODEL / 256, BATCH), 256, 0, stream>>>(x, xp, delta, Alog, Dv, P, out);
}

// Round 4
// 317.149 us; speedup vs baseline: 2.9020x; 1.5620x over previous
//
#include <hip/hip_runtime.h>
#include <cstddef>

#define D_MODEL 1024
#define D_STATE 16
#define DT_RANK 64
#define BATCH 4
#define SEQ 4096
#define NPROJ 96                 // DT_RANK + 2*D_STATE
#define M_TOTAL (BATCH * SEQ)    // 16384
#define NCHUNK 64
#define CLEN 64                  // SEQ / NCHUNK
#define KSPLIT 4
#define KSLICE 256               // 1024 / KSPLIT

__device__ __forceinline__ float softplus_fast(float v) {
    // max(v,0) + log(1+exp(-|v|)) — stable, hardware exp/log (err ~1e-6, thr=4.0)
    return fmaxf(v, 0.0f) + __logf(1.0f + __expf(-fabsf(v)));
}

// ---------------- GEMM1 (split-K): part[ks][m,p] = sum_{k in slice} x[m,k]*W[p,k]
// M=16384, N=96, Kslice=256. BM=64, BN=96, BK=32. 256 thr, 4x6/thread.
// grid (256, KSPLIT) = 1024 blocks -> 4 blocks/CU x 4 waves = 16 waves/CU.
__global__ __launch_bounds__(256) void proj_part_kernel(const float* __restrict__ x,
                                                        const float* __restrict__ W,
                                                        float* __restrict__ part) {
    __shared__ float xs_t[32][68];    // [k][row] transposed, a-frag = ds_read_b128
    __shared__ float ws_t[32][100];   // [k][col] transposed, b-frag = 3x ds_read_b64
    const int tid   = threadIdx.x;
    const int row0  = blockIdx.x * 64;
    const int ks    = blockIdx.y;
    const int kbase = ks * KSLICE;
    const int ty = tid >> 4;   // 0..15 -> rows ty*4..+3
    const int tx = tid & 15;   // cols tx*6..+5

    float acc[4][6];
#pragma unroll
    for (int i = 0; i < 4; ++i)
#pragma unroll
        for (int j = 0; j < 6; ++j) acc[i][j] = 0.0f;

    for (int k0 = kbase; k0 < kbase + KSLICE; k0 += 32) {
        // stage x tile transposed: 64 rows x 32 k (512 float4, 2/thread)
        for (int i = tid; i < 64 * 8; i += 256) {
            int r = i >> 3, c4 = i & 7;
            float4 v = *reinterpret_cast<const float4*>(
                &x[(size_t)(row0 + r) * 1024 + k0 + c4 * 4]);
            xs_t[c4 * 4 + 0][r] = v.x; xs_t[c4 * 4 + 1][r] = v.y;
            xs_t[c4 * 4 + 2][r] = v.z; xs_t[c4 * 4 + 3][r] = v.w;
        }
        // stage W tile transposed: 96 cols x 32 k (768 float4, 3/thread)
        for (int i = tid; i < 96 * 8; i += 256) {
            int r = i >> 3, c4 = i & 7;
            float4 v = *reinterpret_cast<const float4*>(
                &W[(size_t)r * 1024 + k0 + c4 * 4]);
            ws_t[c4 * 4 + 0][r] = v.x; ws_t[c4 * 4 + 1][r] = v.y;
            ws_t[c4 * 4 + 2][r] = v.z; ws_t[c4 * 4 + 3][r] = v.w;
        }
        __syncthreads();
#pragma unroll 8
        for (int k = 0; k < 32; ++k) {
            float4 av = *reinterpret_cast<const float4*>(&xs_t[k][ty * 4]);
            float2 b0 = *reinterpret_cast<const float2*>(&ws_t[k][tx * 6]);
            float2 b1 = *reinterpret_cast<const float2*>(&ws_t[k][tx * 6 + 2]);
            float2 b2 = *reinterpret_cast<const float2*>(&ws_t[k][tx * 6 + 4]);
            float a[4] = {av.x, av.y, av.z, av.w};
            float b[6] = {b0.x, b0.y, b1.x, b1.y, b2.x, b2.y};
#pragma unroll
            for (int i = 0; i < 4; ++i)
#pragma unroll
                for (int j = 0; j < 6; ++j) acc[i][j] = fmaf(a[i], b[j], acc[i][j]);
        }
        __syncthreads();
    }
    size_t base = ((size_t)ks * M_TOTAL + row0) * NPROJ;
#pragma unroll
    for (int i = 0; i < 4; ++i) {
        size_t rbase = base + (size_t)(ty * 4 + i) * NPROJ + tx * 6;
#pragma unroll
        for (int j = 0; j < 6; ++j) part[rbase + j] = acc[i][j];
    }
}

// ---------------- reduce: xp = sum_ks part[ks]  (float4 grid) ----------------
__global__ __launch_bounds__(256) void reduce_xp_kernel(const float* __restrict__ part,
                                                        float* __restrict__ xp) {
    const size_t stride4 = (size_t)M_TOTAL * NPROJ / 4;   // float4 elements per slice
    size_t i = (size_t)blockIdx.x * 256 + threadIdx.x;    // exactly M_TOTAL*NPROJ/4 threads
    const float4* p = reinterpret_cast<const float4*>(part);
    float4 a = p[i];
    float4 b = p[i + stride4];
    float4 c = p[i + 2 * stride4];
    float4 d = p[i + 3 * stride4];
    float4 o;
    o.x = (a.x + b.x) + (c.x + d.x);
    o.y = (a.y + b.y) + (c.y + d.y);
    o.z = (a.z + b.z) + (c.z + d.z);
    o.w = (a.w + b.w) + (c.w + d.w);
    reinterpret_cast<float4*>(xp)[i] = o;
}

// ------- GEMM2: delta[m,d] = softplus( sum_r xp[m,r]*Wd[d,r] + b_dt[d] ) ----
// M=16384, N=1024, K=64. BM=128, BN=128, BK=32 (2 tiles). 256 thr, 8x8/thread.
__global__ __launch_bounds__(256) void delta_kernel(const float* __restrict__ xp,
                                                    const float* __restrict__ Wd,
                                                    const float* __restrict__ b_dt,
                                                    float* __restrict__ delta) {
    __shared__ float as_t[32][132];  // [k][row]
    __shared__ float bs_t[32][132];  // [k][col]
    const int tid  = threadIdx.x;
    const int row0 = blockIdx.x * 128;
    const int col0 = blockIdx.y * 128;
    const int ty = tid >> 4;   // rows ty*8..+7
    const int tx = tid & 15;   // cols tx*8..+7

    float acc[8][8];
#pragma unroll
    for (int i = 0; i < 8; ++i)
#pragma unroll
        for (int j = 0; j < 8; ++j) acc[i][j] = 0.0f;

    for (int k0 = 0; k0 < 64; k0 += 32) {
        for (int i = tid; i < 128 * 8; i += 256) {
            int r = i >> 3, c4 = i & 7;
            float4 v = *reinterpret_cast<const float4*>(
                &xp[(size_t)(row0 + r) * NPROJ + k0 + c4 * 4]);
            as_t[c4 * 4 + 0][r] = v.x; as_t[c4 * 4 + 1][r] = v.y;
            as_t[c4 * 4 + 2][r] = v.z; as_t[c4 * 4 + 3][r] = v.w;
        }
        for (int i = tid; i < 128 * 8; i += 256) {
            int r = i >> 3, c4 = i & 7;
            float4 v = *reinterpret_cast<const float4*>(
                &Wd[(size_t)(col0 + r) * 64 + k0 + c4 * 4]);
            bs_t[c4 * 4 + 0][r] = v.x; bs_t[c4 * 4 + 1][r] = v.y;
            bs_t[c4 * 4 + 2][r] = v.z; bs_t[c4 * 4 + 3][r] = v.w;
        }
        __syncthreads();
#pragma unroll 4
        for (int k = 0; k < 32; ++k) {
            float4 a0 = *reinterpret_cast<const float4*>(&as_t[k][ty * 8]);
            float4 a1 = *reinterpret_cast<const float4*>(&as_t[k][ty * 8 + 4]);
            float4 b0 = *reinterpret_cast<const float4*>(&bs_t[k][tx * 8]);
            float4 b1 = *reinterpret_cast<const float4*>(&bs_t[k][tx * 8 + 4]);
            float a[8] = {a0.x, a0.y, a0.z, a0.w, a1.x, a1.y, a1.z, a1.w};
            float b[8] = {b0.x, b0.y, b0.z, b0.w, b1.x, b1.y, b1.z, b1.w};
#pragma unroll
            for (int i = 0; i < 8; ++i)
#pragma unroll
                for (int j = 0; j < 8; ++j) acc[i][j] = fmaf(a[i], b[j], acc[i][j]);
        }
        __syncthreads();
    }

    float4 bias0 = *reinterpret_cast<const float4*>(&b_dt[col0 + tx * 8]);
    float4 bias1 = *reinterpret_cast<const float4*>(&b_dt[col0 + tx * 8 + 4]);
#pragma unroll
    for (int i = 0; i < 8; ++i) {
        int row = row0 + ty * 8 + i;
        float4 o0, o1;
        o0.x = softplus_fast(acc[i][0] + bias0.x);
        o0.y = softplus_fast(acc[i][1] + bias0.y);
        o0.z = softplus_fast(acc[i][2] + bias0.z);
        o0.w = softplus_fast(acc[i][3] + bias0.w);
        o1.x = softplus_fast(acc[i][4] + bias1.x);
        o1.y = softplus_fast(acc[i][5] + bias1.y);
        o1.z = softplus_fast(acc[i][6] + bias1.z);
        o1.w = softplus_fast(acc[i][7] + bias1.w);
        float* dst = &delta[(size_t)row * D_MODEL + col0 + tx * 8];
        *reinterpret_cast<float4*>(dst)     = o0;
        *reinterpret_cast<float4*>(dst + 4) = o1;
    }
}

// ---------------- Scan pass A: per-chunk transfer (Prod a, h_local) --------
__global__ __launch_bounds__(256) void scanA_kernel(const float* __restrict__ x,
                                                    const float* __restrict__ xp,
                                                    const float* __restrict__ delta,
                                                    const float* __restrict__ A_log,
                                                    float* __restrict__ P,
                                                    float* __restrict__ H) {
    const int chunk = blockIdx.x;
    const int b     = blockIdx.z;
    const int d     = blockIdx.y * 256 + threadIdx.x;

    float Av[16];
    const float4* Arow = reinterpret_cast<const float4*>(A_log + (size_t)d * D_STATE);
#pragma unroll
    for (int q = 0; q < 4; ++q) {
        float4 v = Arow[q];
        Av[q * 4 + 0] = -__expf(v.x); Av[q * 4 + 1] = -__expf(v.y);
        Av[q * 4 + 2] = -__expf(v.z); Av[q * 4 + 3] = -__expf(v.w);
    }
    float h[16];
#pragma unroll
    for (int n = 0; n < 16; ++n) h[n] = 0.0f;
    float sdv = 0.0f;

    const size_t m0 = (size_t)b * SEQ + (size_t)chunk * CLEN;
#pragma unroll 2
    for (int j = 0; j < CLEN; ++j) {
        size_t m = m0 + j;
        float dv = delta[m * D_MODEL + d];
        float xv = x[m * D_MODEL + d];
        float dtx = dv * xv;
        const float4* Bp = reinterpret_cast<const float4*>(xp + m * NPROJ + DT_RANK);
        float Bv[16];
        {
            float4 v0 = Bp[0], v1 = Bp[1], v2 = Bp[2], v3 = Bp[3];
            Bv[0]=v0.x; Bv[1]=v0.y; Bv[2]=v0.z; Bv[3]=v0.w;
            Bv[4]=v1.x; Bv[5]=v1.y; Bv[6]=v1.z; Bv[7]=v1.w;
            Bv[8]=v2.x; Bv[9]=v2.y; Bv[10]=v2.z; Bv[11]=v2.w;
            Bv[12]=v3.x; Bv[13]=v3.y; Bv[14]=v3.z; Bv[15]=v3.w;
        }
        sdv += dv;
#pragma unroll
        for (int n = 0; n < 16; ++n) {
            float a = __expf(dv * Av[n]);
            h[n] = fmaf(a, h[n], dtx * Bv[n]);
        }
    }
    size_t idx = (((size_t)chunk * BATCH + b) * D_MODEL + d) * D_STATE;
    float4* Pp = reinterpret_cast<float4*>(P + idx);
    float4* Hp = reinterpret_cast<float4*>(H + idx);
#pragma unroll
    for (int q = 0; q < 4; ++q) {
        float4 pv, hv;
        pv.x = __expf(Av[q*4+0] * sdv); pv.y = __expf(Av[q*4+1] * sdv);
        pv.z = __expf(Av[q*4+2] * sdv); pv.w = __expf(Av[q*4+3] * sdv);
        hv.x = h[q*4+0]; hv.y = h[q*4+1]; hv.z = h[q*4+2]; hv.w = h[q*4+3];
        Pp[q] = pv; Hp[q] = hv;
    }
}

// ---------------- Scan pass B: inter-chunk scan; rewrites P <- carry-in ----
__global__ __launch_bounds__(256) void scanB_kernel(float* __restrict__ P,
                                                    const float* __restrict__ H) {
    const int t = blockIdx.x * 256 + threadIdx.x;   // (b*1024+d)*16+n
    float carry = 0.0f;
    for (int c = 0; c < NCHUNK; ++c) {
        size_t idx = (size_t)c * (BATCH * D_MODEL * D_STATE) + t;
        float p  = P[idx];
        float hh = H[idx];
        P[idx] = carry;                       // carry-in for this chunk
        carry = fmaf(p, carry, hh);
    }
}

// ---------------- Scan pass C: replay with carry-in, produce y -------------
__global__ __launch_bounds__(256) void scanC_kernel(const float* __restrict__ x,
                                                    const float* __restrict__ xp,
                                                    const float* __restrict__ delta,
                                                    const float* __restrict__ A_log,
                                                    const float* __restrict__ Dvec,
                                                    const float* __restrict__ Hin,
                                                    float* __restrict__ out) {
    const int chunk = blockIdx.x;
    const int b     = blockIdx.z;
    const int d     = blockIdx.y * 256 + threadIdx.x;

    float Av[16];
    const float4* Arow = reinterpret_cast<const float4*>(A_log + (size_t)d * D_STATE);
#pragma unroll
    for (int q = 0; q < 4; ++q) {
        float4 v = Arow[q];
        Av[q * 4 + 0] = -__expf(v.x); Av[q * 4 + 1] = -__expf(v.y);
        Av[q * 4 + 2] = -__expf(v.z); Av[q * 4 + 3] = -__expf(v.w);
    }
    const float Dv = Dvec[d];

    float h[16];
    size_t idx = (((size_t)chunk * BATCH + b) * D_MODEL + d) * D_STATE;
    const float4* Hp = reinterpret_cast<const float4*>(Hin + idx);
#pragma unroll
    for (int q = 0; q < 4; ++q) {
        float4 v = Hp[q];
        h[q*4+0] = v.x; h[q*4+1] = v.y; h[q*4+2] = v.z; h[q*4+3] = v.w;
    }

    const size_t m0 = (size_t)b * SEQ + (size_t)chunk * CLEN;
#pragma unroll 2
    for (int j = 0; j < CLEN; ++j) {
        size_t m = m0 + j;
        float dv = delta[m * D_MODEL + d];
        float xv = x[m * D_MODEL + d];
        float dtx = dv * xv;
        const float4* Bp = reinterpret_cast<const float4*>(xp + m * NPROJ + DT_RANK);
        float Bv[16], Cv[16];
        {
            float4 v0 = Bp[0], v1 = Bp[1], v2 = Bp[2], v3 = Bp[3];
            Bv[0]=v0.x; Bv[1]=v0.y; Bv[2]=v0.z; Bv[3]=v0.w;
            Bv[4]=v1.x; Bv[5]=v1.y; Bv[6]=v1.z; Bv[7]=v1.w;
            Bv[8]=v2.x; Bv[9]=v2.y; Bv[10]=v2.z; Bv[11]=v2.w;
            Bv[12]=v3.x; Bv[13]=v3.y; Bv[14]=v3.z; Bv[15]=v3.w;
            float4 c0 = Bp[4], c1 = Bp[5], c2 = Bp[6], c3 = Bp[7];
            Cv[0]=c0.x; Cv[1]=c0.y; Cv[2]=c0.z; Cv[3]=c0.w;
            Cv[4]=c1.x; Cv[5]=c1.y; Cv[6]=c1.z; Cv[7]=c1.w;
            Cv[8]=c2.x; Cv[9]=c2.y; Cv[10]=c2.z; Cv[11]=c2.w;
            Cv[12]=c3.x; Cv[13]=c3.y; Cv[14]=c3.z; Cv[15]=c3.w;
        }
        float y = 0.0f;
#pragma unroll
        for (int n = 0; n < 16; ++n) {
            float a = __expf(dv * Av[n]);
            h[n] = fmaf(a, h[n], dtx * Bv[n]);
            y = fmaf(h[n], Cv[n], y);
        }
        out[m * D_MODEL + d] = fmaf(xv, Dv, y);
    }
}

extern "C" void kernel_launch(void* const* d_in, const int* in_sizes, int n_in,
                              void* d_out, int out_size, void* d_ws, size_t ws_size,
                              hipStream_t stream) {
    const float* x    = (const float*)d_in[0];
    const float* Wx   = (const float*)d_in[1];
    const float* Wd   = (const float*)d_in[2];
    const float* bdt  = (const float*)d_in[3];
    const float* Alog = (const float*)d_in[4];
    const float* Dv   = (const float*)d_in[5];
    float* out = (float*)d_out;

    float* ws    = (float*)d_ws;
    float* xp    = ws;                                        // 16384*96
    float* delta = xp + (size_t)M_TOTAL * NPROJ;              // 16384*1024
    float* P     = delta + (size_t)M_TOTAL * D_MODEL;         // 64*4*1024*16
    float* H     = P + (size_t)NCHUNK * BATCH * D_MODEL * D_STATE;
    // split-K partials (4 * 16384 * 96 = 25.2 MB) alias onto P+H (33.6 MB):
    // they are dead once reduce_xp has run, before scanA writes P/H.
    float* part  = P;

    proj_part_kernel<<<dim3(M_TOTAL / 64, KSPLIT), 256, 0, stream>>>(x, Wx, part);
    reduce_xp_kernel<<<dim3((M_TOTAL * NPROJ / 4) / 256), 256, 0, stream>>>(part, xp);
    delta_kernel<<<dim3(M_TOTAL / 128, D_MODEL / 128), 256, 0, stream>>>(xp, Wd, bdt, delta);
    scanA_kernel<<<dim3(NCHUNK, D_MODEL / 256, BATCH), 256, 0, stream>>>(x, xp, delta, Alog, P, H);
    scanB_kernel<<<dim3((BATCH * D_MODEL * D_STATE) / 256), 256, 0, stream>>>(P, H);
    scanC_kernel<<<dim3(NCHUNK, D_MODEL / 256, BATCH), 256, 0, stream>>>(x, xp, delta, Alog, Dv, P, out);
}